// Round 10
// baseline (184.027 us; speedup 1.0000x reference)
//
#include <hip/hip_runtime.h>
#include <hip/hip_bf16.h>

// A=2048 assets, F=2048 flat dim.
//   q = z@Wq^T + bq ; k = z@Wk^T + bk ; v = z@Wv^T + bv
//   S = (q@k^T)/8 ; P = softmax_rows(S) ; h = P@v
// All GEMMs NT (A[m][k].B[n][k]) bf16 MFMA, f32 accum; v materialized as vT.
// Round 10 = round 9 + ONE change: QKV occupancy max-out.
//   QKV: 128x64 tiles, 8 waves, dbuf 24KB -> 1536 blocks (z folded fastest
//   into blockIdx.x for A-panel L2 reuse), 4 blk/CU x 8 waves = 32 waves/CU.
// Keeps r9's conflict-free XOR swizzle (conflicts measured 0) on both sides.
//
// ws (32 MB) liveness:
//   [0:8)   zb   (dead after QKV)  -> S f32 [0:16)
//   [8:16)  Wqb  (dead after QKV)  ->   S cont'd
//   [16:24) Wkb  (dead after QKV)  -> P bf16
//   [24:32) vT   (written by QKV z=2, live until PV)
//   d_out: qb[0:8) + kb[8:16) bf16 (dead after scores) -> final h f32 (PV)
// Wv is consumed f32 directly (reg-stage+cvt B-side, z=2 blocks only).

#define AD 2048
#define FD 2048
constexpr float SM_SCALE = 0.125f;   // 64^-0.5

typedef __attribute__((ext_vector_type(8))) short bf16x8;
typedef __attribute__((ext_vector_type(4))) float f32x4;

__device__ __forceinline__ unsigned short f2bf(float f) {
  union { float f; unsigned u; } x; x.f = f;
  unsigned r = x.u + 0x7fffu + ((x.u >> 16) & 1u);   // RNE
  return (unsigned short)(r >> 16);
}

typedef __attribute__((address_space(1))) const void GVOID;
typedef __attribute__((address_space(3))) void LVOID;

__device__ __forceinline__ void gload16(const void* g, void* l) {
  __builtin_amdgcn_global_load_lds((GVOID*)g, (LVOID*)l, 16, 0, 0);
}

struct GemmArgs {
  const void* A;
  const void* B[3];
  const float* bias[3];
  void* out[3];
  int outmode[3];   // 0 = f32 row-major (xscale), 1 = bf16 row-major (+bias), 2 = bf16 C^T (+bias)
  int bf32mask;     // bit z: B[z] is f32 (reg-stage + cvt)
  float scale;
};

// Wave grid WROWS x WCOLS, wave tile (MREP*16) x (NREP*16), BK=32, dbuf LDS.
// FORCE_MODE >= 0: compile single epilogue; -1: runtime args.outmode[z].
// NZ > 0: z folded fastest into blockIdx.x (bn = bx / NZ, z = bx % NZ).
template<int WROWS, int WCOLS, int MREP, int NREP, int FORCE_MODE, bool MIXEDB, int W2, int NZ>
__global__ __launch_bounds__(WROWS*WCOLS*64, W2) void gemm_d(GemmArgs args) {
  constexpr int NT = WROWS * WCOLS * 64;
  constexpr int BM = WROWS * MREP * 16;
  constexpr int BN = WCOLS * NREP * 16;
  constexpr int SA = BM * 4;            // 16B slices per A K-tile
  constexpr int SB = BN * 4;
  static_assert(SA >= NT && SA % NT == 0, "A staging full-coverage");
  static_assert(SB >= NT || (SB % 64 == 0), "B staging wave-granular");

  __shared__ __hip_bfloat16 lA[2][BM * 32];
  __shared__ __hip_bfloat16 lB[2][BN * 32];

  int bnx = blockIdx.x, z;
  if constexpr (NZ > 0) { z = bnx % NZ; bnx /= NZ; }
  else                  { z = blockIdx.z; }
  const int bn = bnx, bm = blockIdx.y;

  const __hip_bfloat16* __restrict__ A = (const __hip_bfloat16*)args.A;
  const __hip_bfloat16* __restrict__ B = (const __hip_bfloat16*)args.B[z];
  const float*          __restrict__ Bf = (const float*)args.B[z];

  const int t    = threadIdx.x;
  const int lane = t & 63;
  const int wv   = t >> 6;
  const int wr   = wv / WCOLS;
  const int wc   = wv % WCOLS;
  const int fr   = lane & 15;
  const int s2   = lane >> 4;          // logical 16B k-group 0..3

  bool dof32 = false;
  if constexpr (MIXEDB) dof32 = (args.bf32mask >> z) & 1;

  f32x4 acc[MREP][NREP] = {};

  // swizzled source column for slice s (row = s>>2, physical slot = s&3):
  // physical slot p holds logical group p ^ ((row>>1)&3)
  auto scol = [](int s) { return (((s & 3) ^ ((s >> 3) & 3)) * 8); };

  auto STAGE = [&](int k0, int buf) {
    #pragma unroll
    for (int r = 0; r < SA / NT; ++r) {
      const int s = t + r * NT;
      gload16(A + (size_t)(bm * BM + (s >> 2)) * FD + k0 + scol(s), &lA[buf][s * 8]);
    }
    if constexpr (MIXEDB) {
      if (dof32) {
        #pragma unroll
        for (int r = 0; r < (SB + NT - 1) / NT; ++r) {
          const int s = t + r * NT;
          if (SB >= NT || t < SB) {
            const float* src = Bf + (size_t)(bn * BN + (s >> 2)) * FD + k0 + scol(s);
            const float4 x = *reinterpret_cast<const float4*>(src);
            const float4 y = *reinterpret_cast<const float4*>(src + 4);
            union { unsigned short us[8]; int4 v; } pk;
            pk.us[0] = f2bf(x.x); pk.us[1] = f2bf(x.y); pk.us[2] = f2bf(x.z); pk.us[3] = f2bf(x.w);
            pk.us[4] = f2bf(y.x); pk.us[5] = f2bf(y.y); pk.us[6] = f2bf(y.z); pk.us[7] = f2bf(y.w);
            *reinterpret_cast<int4*>(&lB[buf][s * 8]) = pk.v;
          }
        }
        return;
      }
    }
    #pragma unroll
    for (int r = 0; r < (SB + NT - 1) / NT; ++r) {
      const int s = t + r * NT;
      if (SB >= NT || t < SB)   // wave-granular mask (SB % 64 == 0)
        gload16(B + (size_t)(bn * BN + (s >> 2)) * FD + k0 + scol(s), &lB[buf][s * 8]);
    }
  };

  auto COMPUTE = [&](int buf) {
    bf16x8 af[MREP], bfr[NREP];
    #pragma unroll
    for (int m = 0; m < MREP; ++m) {
      const int row = wr * (MREP * 16) + m * 16 + fr;
      af[m] = *reinterpret_cast<const bf16x8*>(
          &lA[buf][row * 32 + ((s2 ^ ((row >> 1) & 3)) * 8)]);
    }
    #pragma unroll
    for (int n = 0; n < NREP; ++n) {
      const int row = wc * (NREP * 16) + n * 16 + fr;
      bfr[n] = *reinterpret_cast<const bf16x8*>(
          &lB[buf][row * 32 + ((s2 ^ ((row >> 1) & 3)) * 8)]);
    }
    #pragma unroll
    for (int m = 0; m < MREP; ++m)
      #pragma unroll
      for (int n = 0; n < NREP; ++n)
        acc[m][n] = __builtin_amdgcn_mfma_f32_16x16x32_bf16(af[m], bfr[n], acc[m][n], 0, 0, 0);
  };

  STAGE(0, 0);
  __syncthreads();
  int cur = 0;
  for (int k0 = 32; k0 < FD; k0 += 32) {
    STAGE(k0, cur ^ 1);     // prefetch next tile (in flight during COMPUTE)
    COMPUTE(cur);
    __syncthreads();        // drains prefetch + all frag reads of cur
    cur ^= 1;
  }
  COMPUTE(cur);

  // Epilogue. C/D mapping (m89-verified): col = lane&15, row = (lane>>4)*4 + j
  const float scale = args.scale;
  const float* __restrict__ bias = args.bias[z];
  const int mode = (FORCE_MODE >= 0) ? FORCE_MODE : args.outmode[z];
  const int row0 = bm * BM + wr * (MREP * 16) + (lane >> 4) * 4;
  const int col0 = bn * BN + wc * (NREP * 16) + fr;

  if (mode == 0) {
    float* __restrict__ out = (float*)args.out[z];
    #pragma unroll
    for (int m = 0; m < MREP; ++m)
      #pragma unroll
      for (int n = 0; n < NREP; ++n) {
        const int cg = col0 + n * 16;
        #pragma unroll
        for (int j = 0; j < 4; ++j)
          out[(size_t)(row0 + m * 16 + j) * FD + cg] = acc[m][n][j] * scale;
      }
  } else if (mode == 1) {
    __hip_bfloat16* __restrict__ out = (__hip_bfloat16*)args.out[z];
    #pragma unroll
    for (int m = 0; m < MREP; ++m)
      #pragma unroll
      for (int n = 0; n < NREP; ++n) {
        const int cg = col0 + n * 16;
        const float badd = bias[cg];
        #pragma unroll
        for (int j = 0; j < 4; ++j) {
          unsigned short b16 = f2bf(acc[m][n][j] + badd);
          out[(size_t)(row0 + m * 16 + j) * FD + cg] = *reinterpret_cast<__hip_bfloat16*>(&b16);
        }
      }
  } else { // mode == 2: store C^T -> vT[f][a]; 4 consecutive rows = one 8B store
    __hip_bfloat16* __restrict__ out = (__hip_bfloat16*)args.out[z];
    #pragma unroll
    for (int m = 0; m < MREP; ++m)
      #pragma unroll
      for (int n = 0; n < NREP; ++n) {
        const int cg = col0 + n * 16;   // F index -> row of vT
        const int rg = row0 + m * 16;   // asset index -> col of vT
        const float badd = bias[cg];
        ushort4 pk;
        pk.x = f2bf(acc[m][n][0] + badd);
        pk.y = f2bf(acc[m][n][1] + badd);
        pk.z = f2bf(acc[m][n][2] + badd);
        pk.w = f2bf(acc[m][n][3] + badd);
        *reinterpret_cast<ushort4*>(out + (size_t)cg * AD + rg) = pk;
      }
  }
}

// convert z, Wq, Wk (f32) -> bf16 [zb | Wqb | Wkb], 4M elems each
__global__ __launch_bounds__(256) void cvt_bf16(const float* __restrict__ z,
                                                const float* __restrict__ wq,
                                                const float* __restrict__ wk,
                                                __hip_bfloat16* __restrict__ dst) {
  const size_t NITEM = (size_t)3 * 4096 * 1024 / 8;
  const size_t step = (size_t)gridDim.x * blockDim.x;
  for (size_t idx = (size_t)blockIdx.x * blockDim.x + threadIdx.x; idx < NITEM; idx += step) {
    const int ten = (int)(idx >> 19);
    const size_t off = (idx & ((1u << 19) - 1)) * 8;
    const float* src = (ten == 0) ? z : (ten == 1) ? wq : wk;
    const float4 a = *reinterpret_cast<const float4*>(src + off);
    const float4 b = *reinterpret_cast<const float4*>(src + off + 4);
    union { unsigned short us[8]; int4 v; } pk;
    pk.us[0] = f2bf(a.x); pk.us[1] = f2bf(a.y); pk.us[2] = f2bf(a.z); pk.us[3] = f2bf(a.w);
    pk.us[4] = f2bf(b.x); pk.us[5] = f2bf(b.y); pk.us[6] = f2bf(b.z); pk.us[7] = f2bf(b.w);
    *reinterpret_cast<int4*>(dst + (size_t)ten * 4096 * 1024 + off) = pk.v;
  }
}

__global__ __launch_bounds__(256) void softmax_rows(const float* __restrict__ S,
                                                    __hip_bfloat16* __restrict__ P) {
  const int row = blockIdx.x;
  const int t = threadIdx.x;
  const float* s = S + (size_t)row * AD + t * 8;
  const float4 v0 = *reinterpret_cast<const float4*>(s);
  const float4 v1 = *reinterpret_cast<const float4*>(s + 4);
  float vals[8] = {v0.x, v0.y, v0.z, v0.w, v1.x, v1.y, v1.z, v1.w};

  float m = vals[0];
  #pragma unroll
  for (int j = 1; j < 8; ++j) m = fmaxf(m, vals[j]);
  #pragma unroll
  for (int off = 32; off >= 1; off >>= 1) m = fmaxf(m, __shfl_xor(m, off));

  __shared__ float redm[4], reds[4];
  if ((t & 63) == 0) redm[t >> 6] = m;
  __syncthreads();
  m = fmaxf(fmaxf(redm[0], redm[1]), fmaxf(redm[2], redm[3]));

  float e[8];
  float sum = 0.f;
  #pragma unroll
  for (int j = 0; j < 8; ++j) { e[j] = __expf(vals[j] - m); sum += e[j]; }
  #pragma unroll
  for (int off = 32; off >= 1; off >>= 1) sum += __shfl_xor(sum, off);
  if ((t & 63) == 0) reds[t >> 6] = sum;
  __syncthreads();
  sum = reds[0] + reds[1] + reds[2] + reds[3];
  const float inv = 1.f / sum;

  union { unsigned short us[8]; int4 v; } pk;
  #pragma unroll
  for (int j = 0; j < 8; ++j) pk.us[j] = f2bf(e[j] * inv);
  *reinterpret_cast<int4*>(P + (size_t)row * AD + t * 8) = pk.v;
}

extern "C" void kernel_launch(void* const* d_in, const int* in_sizes, int n_in,
                              void* d_out, int out_size, void* d_ws, size_t ws_size,
                              hipStream_t stream) {
  const float* z  = (const float*)d_in[0];
  const float* Wq = (const float*)d_in[1];
  const float* bq = (const float*)d_in[2];
  const float* Wk = (const float*)d_in[3];
  const float* bk = (const float*)d_in[4];
  const float* Wv = (const float*)d_in[5];
  const float* bv = (const float*)d_in[6];

  char* ws = (char*)d_ws;
  const size_t MB8 = (size_t)8 * 1024 * 1024;
  __hip_bfloat16* zb  = (__hip_bfloat16*)(ws);            // dead after QKV
  __hip_bfloat16* Wqb = (__hip_bfloat16*)(ws + MB8);      // dead after QKV
  __hip_bfloat16* Wkb = (__hip_bfloat16*)(ws + 2*MB8);    // dead after QKV
  __hip_bfloat16* vT  = (__hip_bfloat16*)(ws + 3*MB8);    // live until PV
  float*          S   = (float*)(ws);                     // over zb+Wqb (16MB)
  __hip_bfloat16* P   = (__hip_bfloat16*)(ws + 2*MB8);    // over Wkb
  __hip_bfloat16* qb  = (__hip_bfloat16*)d_out;           // d_out scratch [0:8)MB
  __hip_bfloat16* kb  = (__hip_bfloat16*)d_out + (size_t)AD * FD;  // [8:16)MB

  // 0) convert z, Wq, Wk to bf16 (Wv consumed f32 in-kernel)
  cvt_bf16<<<dim3(2048), dim3(256), 0, stream>>>(z, Wq, Wk, (__hip_bfloat16*)ws);

  // 1) fused QKV: 128x64 tiles, 8 waves, z folded fastest -> 1536 blocks,
  //    4 blk/CU x 8 waves = 32 waves/CU (max occupancy)
  {
    GemmArgs a;
    a.A = zb;
    a.B[0] = Wqb; a.B[1] = Wkb; a.B[2] = Wv;
    a.bias[0] = bq; a.bias[1] = bk; a.bias[2] = bv;
    a.out[0] = qb; a.out[1] = kb; a.out[2] = vT;
    a.outmode[0] = 1; a.outmode[1] = 1; a.outmode[2] = 2;
    a.bf32mask = 0b100;
    a.scale = 1.0f;
    gemm_d<4, 2, 2, 2, -1, true, 8, 3>
        <<<dim3((AD/64) * 3, AD/128, 1), dim3(512), 0, stream>>>(a);
  }
  // 2) scores = (qb @ kb^T)/8 -> f32 S ; 128x64 8-wave, 512 blocks
  {
    GemmArgs a = {};
    a.A = qb;
    a.B[0] = kb;
    a.bias[0] = nullptr;
    a.out[0] = S;
    a.outmode[0] = 0;
    a.bf32mask = 0;
    a.scale = SM_SCALE;
    gemm_d<4, 2, 2, 2, 0, false, 4, 0><<<dim3(AD/64, AD/128, 1), dim3(512), 0, stream>>>(a);
  }
  // 3) row softmax -> P bf16 (over Wkb)
  softmax_rows<<<dim3(AD), dim3(256), 0, stream>>>(S, P);
  // 4) h = P @ vT^T -> f32 d_out ; 128x64 8-wave, 512 blocks
  {
    GemmArgs a = {};
    a.A = P;
    a.B[0] = vT;
    a.bias[0] = nullptr;
    a.out[0] = d_out;
    a.outmode[0] = 0;
    a.bf32mask = 0;
    a.scale = 1.0f;
    gemm_d<4, 2, 2, 2, 0, false, 4, 0><<<dim3(AD/64, AD/128, 1), dim3(512), 0, stream>>>(a);
  }
}

// Round 11
// 152.344 us; speedup vs baseline: 1.2080x; 1.2080x over previous
//
#include <hip/hip_runtime.h>
#include <hip/hip_bf16.h>

// A=2048 assets, F=2048 flat dim.
//   q = z@Wq^T + bq ; k = z@Wk^T + bk ; v = z@Wv^T + bv
//   S = (q@k^T)/8 ; P = softmax_rows(S) ; h = P@v
// All GEMMs NT (A[m][k].B[n][k]) bf16 MFMA, f32 accum; v materialized as vT.
// Round 11: BK=64 (half the barrier/drain events; 2-phase dbuf loop kept),
// 8-slot XOR swizzle (slot ^= row&7, both sides, conflict-free at 128B rows),
// best-measured geometries: QKV 8-wave (2,4) 128^2 z-slow 768 blk;
// scores/PV 8-wave (2,2) 128x64 512 blk.
//
// ws (32 MB) liveness:
//   [0:8)   zb   (dead after QKV)  -> S f32 [0:16)
//   [8:16)  Wqb  (dead after QKV)  ->   S cont'd
//   [16:24) Wkb  (dead after QKV)  -> P bf16
//   [24:32) vT   (written by QKV z=2, live until PV)
//   d_out: qb[0:8) + kb[8:16) bf16 (dead after scores) -> final h f32 (PV)
// Wv is consumed f32 directly (reg-stage+cvt B-side, z=2 blocks only).

#define AD 2048
#define FD 2048
constexpr float SM_SCALE = 0.125f;   // 64^-0.5

typedef __attribute__((ext_vector_type(8))) short bf16x8;
typedef __attribute__((ext_vector_type(4))) float f32x4;

__device__ __forceinline__ unsigned short f2bf(float f) {
  union { float f; unsigned u; } x; x.f = f;
  unsigned r = x.u + 0x7fffu + ((x.u >> 16) & 1u);   // RNE
  return (unsigned short)(r >> 16);
}

typedef __attribute__((address_space(1))) const void GVOID;
typedef __attribute__((address_space(3))) void LVOID;

__device__ __forceinline__ void gload16(const void* g, void* l) {
  __builtin_amdgcn_global_load_lds((GVOID*)g, (LVOID*)l, 16, 0, 0);
}

struct GemmArgs {
  const void* A;
  const void* B[3];
  const float* bias[3];
  void* out[3];
  int outmode[3];   // 0 = f32 row-major (xscale), 1 = bf16 row-major (+bias), 2 = bf16 C^T (+bias)
  int bf32mask;     // bit z: B[z] is f32 (reg-stage + cvt)
  float scale;
};

// BK=64. Wave grid WROWS x WCOLS, wave tile (MREP*16) x (NREP*16), dbuf LDS.
// Row = 8 x 16B slots; swizzle: physical slot p at row r holds logical p^(r&7),
// realized as pre-swizzled GLOBAL source col (gload_lds dest linear, rule #21)
// + same XOR on frag reads. 16 lanes/frag span 16 rows -> 8 slots x2 = 2-way (free).
template<int WROWS, int WCOLS, int MREP, int NREP, int FORCE_MODE, bool MIXEDB, int W2, int NZ>
__global__ __launch_bounds__(WROWS*WCOLS*64, W2) void gemm_d(GemmArgs args) {
  constexpr int NT = WROWS * WCOLS * 64;
  constexpr int BM = WROWS * MREP * 16;
  constexpr int BN = WCOLS * NREP * 16;
  constexpr int SA = BM * 8;            // 16B slices per A K-tile (BK=64)
  constexpr int SB = BN * 8;
  static_assert(SA >= NT && SA % NT == 0, "A staging full-coverage");
  static_assert(SB % NT == 0, "B staging full-coverage");

  __shared__ __hip_bfloat16 lA[2][BM * 64];
  __shared__ __hip_bfloat16 lB[2][BN * 64];

  int bnx = blockIdx.x, z;
  if constexpr (NZ > 0) { z = bnx % NZ; bnx /= NZ; }
  else                  { z = blockIdx.z; }
  const int bn = bnx, bm = blockIdx.y;

  const __hip_bfloat16* __restrict__ A = (const __hip_bfloat16*)args.A;
  const __hip_bfloat16* __restrict__ B = (const __hip_bfloat16*)args.B[z];
  const float*          __restrict__ Bf = (const float*)args.B[z];

  const int t    = threadIdx.x;
  const int lane = t & 63;
  const int wv   = t >> 6;
  const int wr   = wv / WCOLS;
  const int wc   = wv % WCOLS;
  const int fr   = lane & 15;
  const int s2   = lane >> 4;          // logical 16B k-group 0..3 (within K=32)

  bool dof32 = false;
  if constexpr (MIXEDB) dof32 = (args.bf32mask >> z) & 1;

  f32x4 acc[MREP][NREP] = {};

  // swizzled source column (elements) for slice s: row = s>>3, phys slot = s&7
  // holds logical slot (s&7) ^ (row&7)
  auto scol = [](int s) { return (((s & 7) ^ ((s >> 3) & 7)) * 8); };

  auto STAGE = [&](int k0, int buf) {
    #pragma unroll
    for (int r = 0; r < SA / NT; ++r) {
      const int s = t + r * NT;
      gload16(A + (size_t)(bm * BM + (s >> 3)) * FD + k0 + scol(s), &lA[buf][s * 8]);
    }
    if constexpr (MIXEDB) {
      if (dof32) {
        #pragma unroll
        for (int r = 0; r < SB / NT; ++r) {
          const int s = t + r * NT;
          const float* src = Bf + (size_t)(bn * BN + (s >> 3)) * FD + k0 + scol(s);
          const float4 x = *reinterpret_cast<const float4*>(src);
          const float4 y = *reinterpret_cast<const float4*>(src + 4);
          union { unsigned short us[8]; int4 v; } pk;
          pk.us[0] = f2bf(x.x); pk.us[1] = f2bf(x.y); pk.us[2] = f2bf(x.z); pk.us[3] = f2bf(x.w);
          pk.us[4] = f2bf(y.x); pk.us[5] = f2bf(y.y); pk.us[6] = f2bf(y.z); pk.us[7] = f2bf(y.w);
          *reinterpret_cast<int4*>(&lB[buf][s * 8]) = pk.v;
        }
        return;
      }
    }
    #pragma unroll
    for (int r = 0; r < SB / NT; ++r) {
      const int s = t + r * NT;
      gload16(B + (size_t)(bn * BN + (s >> 3)) * FD + k0 + scol(s), &lB[buf][s * 8]);
    }
  };

  auto COMPUTE = [&](int buf) {
    #pragma unroll
    for (int kk = 0; kk < 2; ++kk) {       // two K=32 sub-steps per BK=64 tile
      const int ls = s2 + 4 * kk;          // logical slot 0..7
      bf16x8 af[MREP], bfr[NREP];
      #pragma unroll
      for (int m = 0; m < MREP; ++m) {
        const int row = wr * (MREP * 16) + m * 16 + fr;
        af[m] = *reinterpret_cast<const bf16x8*>(
            &lA[buf][row * 64 + ((ls ^ (row & 7)) * 8)]);
      }
      #pragma unroll
      for (int n = 0; n < NREP; ++n) {
        const int row = wc * (NREP * 16) + n * 16 + fr;
        bfr[n] = *reinterpret_cast<const bf16x8*>(
            &lB[buf][row * 64 + ((ls ^ (row & 7)) * 8)]);
      }
      #pragma unroll
      for (int m = 0; m < MREP; ++m)
        #pragma unroll
        for (int n = 0; n < NREP; ++n)
          acc[m][n] = __builtin_amdgcn_mfma_f32_16x16x32_bf16(af[m], bfr[n], acc[m][n], 0, 0, 0);
    }
  };

  STAGE(0, 0);
  __syncthreads();
  int cur = 0;
  for (int k0 = 64; k0 < FD; k0 += 64) {
    STAGE(k0, cur ^ 1);     // prefetch next tile (in flight during COMPUTE)
    COMPUTE(cur);
    __syncthreads();        // drains prefetch + all frag reads of cur
    cur ^= 1;
  }
  COMPUTE(cur);

  // Epilogue. C/D mapping (m89-verified): col = lane&15, row = (lane>>4)*4 + j
  const float scale = args.scale;
  const float* __restrict__ bias = args.bias[z];
  const int mode = (FORCE_MODE >= 0) ? FORCE_MODE : args.outmode[z];
  const int row0 = bm * BM + wr * (MREP * 16) + (lane >> 4) * 4;
  const int col0 = bn * BN + wc * (NREP * 16) + fr;

  if (mode == 0) {
    float* __restrict__ out = (float*)args.out[z];
    #pragma unroll
    for (int m = 0; m < MREP; ++m)
      #pragma unroll
      for (int n = 0; n < NREP; ++n) {
        const int cg = col0 + n * 16;
        #pragma unroll
        for (int j = 0; j < 4; ++j)
          out[(size_t)(row0 + m * 16 + j) * FD + cg] = acc[m][n][j] * scale;
      }
  } else if (mode == 1) {
    __hip_bfloat16* __restrict__ out = (__hip_bfloat16*)args.out[z];
    #pragma unroll
    for (int m = 0; m < MREP; ++m)
      #pragma unroll
      for (int n = 0; n < NREP; ++n) {
        const int cg = col0 + n * 16;
        const float badd = bias[cg];
        #pragma unroll
        for (int j = 0; j < 4; ++j) {
          unsigned short b16 = f2bf(acc[m][n][j] + badd);
          out[(size_t)(row0 + m * 16 + j) * FD + cg] = *reinterpret_cast<__hip_bfloat16*>(&b16);
        }
      }
  } else { // mode == 2: store C^T -> vT[f][a]; 4 consecutive rows = one 8B store
    __hip_bfloat16* __restrict__ out = (__hip_bfloat16*)args.out[z];
    #pragma unroll
    for (int m = 0; m < MREP; ++m)
      #pragma unroll
      for (int n = 0; n < NREP; ++n) {
        const int cg = col0 + n * 16;   // F index -> row of vT
        const int rg = row0 + m * 16;   // asset index -> col of vT
        const float badd = bias[cg];
        ushort4 pk;
        pk.x = f2bf(acc[m][n][0] + badd);
        pk.y = f2bf(acc[m][n][1] + badd);
        pk.z = f2bf(acc[m][n][2] + badd);
        pk.w = f2bf(acc[m][n][3] + badd);
        *reinterpret_cast<ushort4*>(out + (size_t)cg * AD + rg) = pk;
      }
  }
}

// convert z, Wq, Wk (f32) -> bf16 [zb | Wqb | Wkb], 4M elems each
__global__ __launch_bounds__(256) void cvt_bf16(const float* __restrict__ z,
                                                const float* __restrict__ wq,
                                                const float* __restrict__ wk,
                                                __hip_bfloat16* __restrict__ dst) {
  const size_t NITEM = (size_t)3 * 4096 * 1024 / 8;
  const size_t step = (size_t)gridDim.x * blockDim.x;
  for (size_t idx = (size_t)blockIdx.x * blockDim.x + threadIdx.x; idx < NITEM; idx += step) {
    const int ten = (int)(idx >> 19);
    const size_t off = (idx & ((1u << 19) - 1)) * 8;
    const float* src = (ten == 0) ? z : (ten == 1) ? wq : wk;
    const float4 a = *reinterpret_cast<const float4*>(src + off);
    const float4 b = *reinterpret_cast<const float4*>(src + off + 4);
    union { unsigned short us[8]; int4 v; } pk;
    pk.us[0] = f2bf(a.x); pk.us[1] = f2bf(a.y); pk.us[2] = f2bf(a.z); pk.us[3] = f2bf(a.w);
    pk.us[4] = f2bf(b.x); pk.us[5] = f2bf(b.y); pk.us[6] = f2bf(b.z); pk.us[7] = f2bf(b.w);
    *reinterpret_cast<int4*>(dst + (size_t)ten * 4096 * 1024 + off) = pk.v;
  }
}

__global__ __launch_bounds__(256) void softmax_rows(const float* __restrict__ S,
                                                    __hip_bfloat16* __restrict__ P) {
  const int row = blockIdx.x;
  const int t = threadIdx.x;
  const float* s = S + (size_t)row * AD + t * 8;
  const float4 v0 = *reinterpret_cast<const float4*>(s);
  const float4 v1 = *reinterpret_cast<const float4*>(s + 4);
  float vals[8] = {v0.x, v0.y, v0.z, v0.w, v1.x, v1.y, v1.z, v1.w};

  float m = vals[0];
  #pragma unroll
  for (int j = 1; j < 8; ++j) m = fmaxf(m, vals[j]);
  #pragma unroll
  for (int off = 32; off >= 1; off >>= 1) m = fmaxf(m, __shfl_xor(m, off));

  __shared__ float redm[4], reds[4];
  if ((t & 63) == 0) redm[t >> 6] = m;
  __syncthreads();
  m = fmaxf(fmaxf(redm[0], redm[1]), fmaxf(redm[2], redm[3]));

  float e[8];
  float sum = 0.f;
  #pragma unroll
  for (int j = 0; j < 8; ++j) { e[j] = __expf(vals[j] - m); sum += e[j]; }
  #pragma unroll
  for (int off = 32; off >= 1; off >>= 1) sum += __shfl_xor(sum, off);
  if ((t & 63) == 0) reds[t >> 6] = sum;
  __syncthreads();
  sum = reds[0] + reds[1] + reds[2] + reds[3];
  const float inv = 1.f / sum;

  union { unsigned short us[8]; int4 v; } pk;
  #pragma unroll
  for (int j = 0; j < 8; ++j) pk.us[j] = f2bf(e[j] * inv);
  *reinterpret_cast<int4*>(P + (size_t)row * AD + t * 8) = pk.v;
}

extern "C" void kernel_launch(void* const* d_in, const int* in_sizes, int n_in,
                              void* d_out, int out_size, void* d_ws, size_t ws_size,
                              hipStream_t stream) {
  const float* z  = (const float*)d_in[0];
  const float* Wq = (const float*)d_in[1];
  const float* bq = (const float*)d_in[2];
  const float* Wk = (const float*)d_in[3];
  const float* bk = (const float*)d_in[4];
  const float* Wv = (const float*)d_in[5];
  const float* bv = (const float*)d_in[6];

  char* ws = (char*)d_ws;
  const size_t MB8 = (size_t)8 * 1024 * 1024;
  __hip_bfloat16* zb  = (__hip_bfloat16*)(ws);            // dead after QKV
  __hip_bfloat16* Wqb = (__hip_bfloat16*)(ws + MB8);      // dead after QKV
  __hip_bfloat16* Wkb = (__hip_bfloat16*)(ws + 2*MB8);    // dead after QKV
  __hip_bfloat16* vT  = (__hip_bfloat16*)(ws + 3*MB8);    // live until PV
  float*          S   = (float*)(ws);                     // over zb+Wqb (16MB)
  __hip_bfloat16* P   = (__hip_bfloat16*)(ws + 2*MB8);    // over Wkb
  __hip_bfloat16* qb  = (__hip_bfloat16*)d_out;           // d_out scratch [0:8)MB
  __hip_bfloat16* kb  = (__hip_bfloat16*)d_out + (size_t)AD * FD;  // [8:16)MB

  // 0) convert z, Wq, Wk to bf16 (Wv consumed f32 in-kernel)
  cvt_bf16<<<dim3(2048), dim3(256), 0, stream>>>(z, Wq, Wk, (__hip_bfloat16*)ws);

  // 1) fused QKV: 8-wave (2,4) 128^2, BK=64, z-slow, 768 blocks
  {
    GemmArgs a;
    a.A = zb;
    a.B[0] = Wqb; a.B[1] = Wkb; a.B[2] = Wv;
    a.bias[0] = bq; a.bias[1] = bk; a.bias[2] = bv;
    a.out[0] = qb; a.out[1] = kb; a.out[2] = vT;
    a.outmode[0] = 1; a.outmode[1] = 1; a.outmode[2] = 2;
    a.bf32mask = 0b100;
    a.scale = 1.0f;
    gemm_d<2, 4, 4, 2, -1, true, 2, 0>
        <<<dim3(AD/128, AD/128, 3), dim3(512), 0, stream>>>(a);
  }
  // 2) scores = (qb @ kb^T)/8 -> f32 S ; 128x64 8-wave BK=64, 512 blocks
  {
    GemmArgs a = {};
    a.A = qb;
    a.B[0] = kb;
    a.bias[0] = nullptr;
    a.out[0] = S;
    a.outmode[0] = 0;
    a.bf32mask = 0;
    a.scale = SM_SCALE;
    gemm_d<4, 2, 2, 2, 0, false, 2, 0><<<dim3(AD/64, AD/128, 1), dim3(512), 0, stream>>>(a);
  }
  // 3) row softmax -> P bf16 (over Wkb)
  softmax_rows<<<dim3(AD), dim3(256), 0, stream>>>(S, P);
  // 4) h = P @ vT^T -> f32 d_out ; 128x64 8-wave BK=64, 512 blocks
  {
    GemmArgs a = {};
    a.A = P;
    a.B[0] = vT;
    a.bias[0] = nullptr;
    a.out[0] = d_out;
    a.outmode[0] = 0;
    a.bf32mask = 0;
    a.scale = 1.0f;
    gemm_d<4, 2, 2, 2, 0, false, 2, 0><<<dim3(AD/64, AD/128, 1), dim3(512), 0, stream>>>(a);
  }
}

// Round 12
// 141.150 us; speedup vs baseline: 1.3038x; 1.0793x over previous
//
#include <hip/hip_runtime.h>
#include <hip/hip_bf16.h>

// A=2048 assets, F=2048 flat dim.
//   q = z@Wq^T + bq ; k = z@Wk^T + bk ; v = z@Wv^T + bv
//   S = (q@k^T)/8 ; P = softmax_rows(S) ; h = P@v
// All GEMMs NT (A[m][k].B[n][k]) bf16 MFMA, f32 accum; v materialized as vT.
// Round 12 = round 11 kernel (BK=64, 8-slot both-sides XOR swizzle, 2-phase
// dbuf) with the f32-Wv staging path ELIMINATED: all four inputs pre-converted
// to bf16; QKV split into pure-bf16 QK (fused z=2) + V launches.
//
// ws (32 MB) liveness:
//   [0:8)   zb   (dead after V)     -> P  (bf16, after softmax)
//   [8:16)  Wqb  (dead after QK)    -> vT (bf16, written by V)
//   [16:24) Wkb  (dead after QK)    -> S f32 [16:32)
//   [24:32) Wvb  (dead after V)     -> S cont'd
//   d_out: qb[0:8) + kb[8:16) bf16 (dead after scores) -> final h f32 (PV)

#define AD 2048
#define FD 2048
constexpr float SM_SCALE = 0.125f;   // 64^-0.5

typedef __attribute__((ext_vector_type(8))) short bf16x8;
typedef __attribute__((ext_vector_type(4))) float f32x4;

__device__ __forceinline__ unsigned short f2bf(float f) {
  union { float f; unsigned u; } x; x.f = f;
  unsigned r = x.u + 0x7fffu + ((x.u >> 16) & 1u);   // RNE
  return (unsigned short)(r >> 16);
}

typedef __attribute__((address_space(1))) const void GVOID;
typedef __attribute__((address_space(3))) void LVOID;

__device__ __forceinline__ void gload16(const void* g, void* l) {
  __builtin_amdgcn_global_load_lds((GVOID*)g, (LVOID*)l, 16, 0, 0);
}

struct GemmArgs {
  const void* A;
  const void* B[2];
  const float* bias[2];
  void* out[2];
  float scale;
};

// BK=64. Wave grid WROWS x WCOLS, wave tile (MREP*16) x (NREP*16), dbuf LDS.
// Row = 8 x 16B slots; swizzle: physical slot p at row r holds logical p^(r&7),
// realized as pre-swizzled GLOBAL source col (gload_lds dest linear, rule #21)
// + same XOR on frag reads (conflict-free at 128B row stride; measured 0).
// MODE: 0 = f32 row-major (xscale), 1 = bf16 row-major (+bias), 2 = bf16 C^T (+bias)
template<int WROWS, int WCOLS, int MREP, int NREP, int MODE, int W2>
__global__ __launch_bounds__(WROWS*WCOLS*64, W2) void gemm_d(GemmArgs args) {
  constexpr int NT = WROWS * WCOLS * 64;
  constexpr int BM = WROWS * MREP * 16;
  constexpr int BN = WCOLS * NREP * 16;
  constexpr int SA = BM * 8;            // 16B slices per A K-tile (BK=64)
  constexpr int SB = BN * 8;
  static_assert(SA >= NT && SA % NT == 0, "A staging full-coverage");
  static_assert(SB % NT == 0, "B staging full-coverage");

  __shared__ __hip_bfloat16 lA[2][BM * 64];
  __shared__ __hip_bfloat16 lB[2][BN * 64];

  const int z  = blockIdx.z;
  const int bn = blockIdx.x, bm = blockIdx.y;

  const __hip_bfloat16* __restrict__ A = (const __hip_bfloat16*)args.A;
  const __hip_bfloat16* __restrict__ B = (const __hip_bfloat16*)args.B[z];

  const int t    = threadIdx.x;
  const int lane = t & 63;
  const int wv   = t >> 6;
  const int wr   = wv / WCOLS;
  const int wc   = wv % WCOLS;
  const int fr   = lane & 15;
  const int s2   = lane >> 4;          // logical 16B k-group 0..3 (within K=32)

  f32x4 acc[MREP][NREP] = {};

  // swizzled source column (elements) for slice s: row = s>>3, phys slot = s&7
  // holds logical slot (s&7) ^ (row&7)
  auto scol = [](int s) { return (((s & 7) ^ ((s >> 3) & 7)) * 8); };

  auto STAGE = [&](int k0, int buf) {
    #pragma unroll
    for (int r = 0; r < SA / NT; ++r) {
      const int s = t + r * NT;
      gload16(A + (size_t)(bm * BM + (s >> 3)) * FD + k0 + scol(s), &lA[buf][s * 8]);
    }
    #pragma unroll
    for (int r = 0; r < SB / NT; ++r) {
      const int s = t + r * NT;
      gload16(B + (size_t)(bn * BN + (s >> 3)) * FD + k0 + scol(s), &lB[buf][s * 8]);
    }
  };

  auto COMPUTE = [&](int buf) {
    #pragma unroll
    for (int kk = 0; kk < 2; ++kk) {       // two K=32 sub-steps per BK=64 tile
      const int ls = s2 + 4 * kk;          // logical slot 0..7
      bf16x8 af[MREP], bfr[NREP];
      #pragma unroll
      for (int m = 0; m < MREP; ++m) {
        const int row = wr * (MREP * 16) + m * 16 + fr;
        af[m] = *reinterpret_cast<const bf16x8*>(
            &lA[buf][row * 64 + ((ls ^ (row & 7)) * 8)]);
      }
      #pragma unroll
      for (int n = 0; n < NREP; ++n) {
        const int row = wc * (NREP * 16) + n * 16 + fr;
        bfr[n] = *reinterpret_cast<const bf16x8*>(
            &lB[buf][row * 64 + ((ls ^ (row & 7)) * 8)]);
      }
      #pragma unroll
      for (int m = 0; m < MREP; ++m)
        #pragma unroll
        for (int n = 0; n < NREP; ++n)
          acc[m][n] = __builtin_amdgcn_mfma_f32_16x16x32_bf16(af[m], bfr[n], acc[m][n], 0, 0, 0);
    }
  };

  STAGE(0, 0);
  __syncthreads();
  int cur = 0;
  for (int k0 = 64; k0 < FD; k0 += 64) {
    STAGE(k0, cur ^ 1);     // prefetch next tile (in flight during COMPUTE)
    COMPUTE(cur);
    __syncthreads();        // drains prefetch + all frag reads of cur
    cur ^= 1;
  }
  COMPUTE(cur);

  // Epilogue. C/D mapping (m89-verified): col = lane&15, row = (lane>>4)*4 + j
  const float scale = args.scale;
  const float* __restrict__ bias = args.bias[z];
  const int row0 = bm * BM + wr * (MREP * 16) + (lane >> 4) * 4;
  const int col0 = bn * BN + wc * (NREP * 16) + fr;

  if constexpr (MODE == 0) {
    float* __restrict__ out = (float*)args.out[z];
    #pragma unroll
    for (int m = 0; m < MREP; ++m)
      #pragma unroll
      for (int n = 0; n < NREP; ++n) {
        const int cg = col0 + n * 16;
        #pragma unroll
        for (int j = 0; j < 4; ++j)
          out[(size_t)(row0 + m * 16 + j) * FD + cg] = acc[m][n][j] * scale;
      }
  } else if constexpr (MODE == 1) {
    __hip_bfloat16* __restrict__ out = (__hip_bfloat16*)args.out[z];
    #pragma unroll
    for (int m = 0; m < MREP; ++m)
      #pragma unroll
      for (int n = 0; n < NREP; ++n) {
        const int cg = col0 + n * 16;
        const float badd = bias[cg];
        #pragma unroll
        for (int j = 0; j < 4; ++j) {
          unsigned short b16 = f2bf(acc[m][n][j] + badd);
          out[(size_t)(row0 + m * 16 + j) * FD + cg] = *reinterpret_cast<__hip_bfloat16*>(&b16);
        }
      }
  } else { // MODE == 2: store C^T -> vT[f][a]; 4 consecutive rows = one 8B store
    __hip_bfloat16* __restrict__ out = (__hip_bfloat16*)args.out[z];
    #pragma unroll
    for (int m = 0; m < MREP; ++m)
      #pragma unroll
      for (int n = 0; n < NREP; ++n) {
        const int cg = col0 + n * 16;   // F index -> row of vT
        const int rg = row0 + m * 16;   // asset index -> col of vT
        const float badd = bias[cg];
        ushort4 pk;
        pk.x = f2bf(acc[m][n][0] + badd);
        pk.y = f2bf(acc[m][n][1] + badd);
        pk.z = f2bf(acc[m][n][2] + badd);
        pk.w = f2bf(acc[m][n][3] + badd);
        *reinterpret_cast<ushort4*>(out + (size_t)cg * AD + rg) = pk;
      }
  }
}

// convert z, Wq, Wk, Wv (f32) -> bf16 [zb | Wqb | Wkb | Wvb], 4M elems each
__global__ __launch_bounds__(256) void cvt_bf16(const float* __restrict__ z,
                                                const float* __restrict__ wq,
                                                const float* __restrict__ wk,
                                                const float* __restrict__ wv,
                                                __hip_bfloat16* __restrict__ dst) {
  const size_t NITEM = (size_t)4 * 4096 * 1024 / 8;
  const size_t step = (size_t)gridDim.x * blockDim.x;
  for (size_t idx = (size_t)blockIdx.x * blockDim.x + threadIdx.x; idx < NITEM; idx += step) {
    const int ten = (int)(idx >> 19);
    const size_t off = (idx & ((1u << 19) - 1)) * 8;
    const float* src = (ten == 0) ? z : (ten == 1) ? wq : (ten == 2) ? wk : wv;
    const float4 a = *reinterpret_cast<const float4*>(src + off);
    const float4 b = *reinterpret_cast<const float4*>(src + off + 4);
    union { unsigned short us[8]; int4 v; } pk;
    pk.us[0] = f2bf(a.x); pk.us[1] = f2bf(a.y); pk.us[2] = f2bf(a.z); pk.us[3] = f2bf(a.w);
    pk.us[4] = f2bf(b.x); pk.us[5] = f2bf(b.y); pk.us[6] = f2bf(b.z); pk.us[7] = f2bf(b.w);
    *reinterpret_cast<int4*>(dst + (size_t)ten * 4096 * 1024 + off) = pk.v;
  }
}

__global__ __launch_bounds__(256) void softmax_rows(const float* __restrict__ S,
                                                    __hip_bfloat16* __restrict__ P) {
  const int row = blockIdx.x;
  const int t = threadIdx.x;
  const float* s = S + (size_t)row * AD + t * 8;
  const float4 v0 = *reinterpret_cast<const float4*>(s);
  const float4 v1 = *reinterpret_cast<const float4*>(s + 4);
  float vals[8] = {v0.x, v0.y, v0.z, v0.w, v1.x, v1.y, v1.z, v1.w};

  float m = vals[0];
  #pragma unroll
  for (int j = 1; j < 8; ++j) m = fmaxf(m, vals[j]);
  #pragma unroll
  for (int off = 32; off >= 1; off >>= 1) m = fmaxf(m, __shfl_xor(m, off));

  __shared__ float redm[4], reds[4];
  if ((t & 63) == 0) redm[t >> 6] = m;
  __syncthreads();
  m = fmaxf(fmaxf(redm[0], redm[1]), fmaxf(redm[2], redm[3]));

  float e[8];
  float sum = 0.f;
  #pragma unroll
  for (int j = 0; j < 8; ++j) { e[j] = __expf(vals[j] - m); sum += e[j]; }
  #pragma unroll
  for (int off = 32; off >= 1; off >>= 1) sum += __shfl_xor(sum, off);
  if ((t & 63) == 0) reds[t >> 6] = sum;
  __syncthreads();
  sum = reds[0] + reds[1] + reds[2] + reds[3];
  const float inv = 1.f / sum;

  union { unsigned short us[8]; int4 v; } pk;
  #pragma unroll
  for (int j = 0; j < 8; ++j) pk.us[j] = f2bf(e[j] * inv);
  *reinterpret_cast<int4*>(P + (size_t)row * AD + t * 8) = pk.v;
}

extern "C" void kernel_launch(void* const* d_in, const int* in_sizes, int n_in,
                              void* d_out, int out_size, void* d_ws, size_t ws_size,
                              hipStream_t stream) {
  const float* z  = (const float*)d_in[0];
  const float* Wq = (const float*)d_in[1];
  const float* bq = (const float*)d_in[2];
  const float* Wk = (const float*)d_in[3];
  const float* bk = (const float*)d_in[4];
  const float* Wv = (const float*)d_in[5];
  const float* bv = (const float*)d_in[6];

  char* ws = (char*)d_ws;
  const size_t MB8 = (size_t)8 * 1024 * 1024;
  __hip_bfloat16* zb  = (__hip_bfloat16*)(ws);            // dead after V
  __hip_bfloat16* Wqb = (__hip_bfloat16*)(ws + MB8);      // dead after QK
  __hip_bfloat16* Wkb = (__hip_bfloat16*)(ws + 2*MB8);    // dead after QK
  __hip_bfloat16* Wvb = (__hip_bfloat16*)(ws + 3*MB8);    // dead after V
  __hip_bfloat16* vT  = (__hip_bfloat16*)(ws + MB8);      // over Wqb
  float*          S   = (float*)(ws + 2*MB8);             // over Wkb+Wvb (16MB)
  __hip_bfloat16* P   = (__hip_bfloat16*)(ws);            // over zb
  __hip_bfloat16* qb  = (__hip_bfloat16*)d_out;           // d_out scratch [0:8)MB
  __hip_bfloat16* kb  = (__hip_bfloat16*)d_out + (size_t)AD * FD;  // [8:16)MB

  // 0) convert all four tensors to bf16
  cvt_bf16<<<dim3(2048), dim3(256), 0, stream>>>(z, Wq, Wk, Wv, (__hip_bfloat16*)ws);

  // 1) fused QK (pure bf16): (2,4,4,2) 128^2 BK=64, 512 blocks (~2/CU)
  {
    GemmArgs a;
    a.A = zb;
    a.B[0] = Wqb;  a.B[1] = Wkb;
    a.bias[0] = bq; a.bias[1] = bk;
    a.out[0] = qb;  a.out[1] = kb;
    a.scale = 1.0f;
    gemm_d<2, 4, 4, 2, 1, 2><<<dim3(AD/128, AD/128, 2), dim3(512), 0, stream>>>(a);
  }
  // 2) V (pure bf16): (4,2,2,2) 128x64 BK=64, 512 blocks -> vT over Wqb
  {
    GemmArgs a = {};
    a.A = zb;
    a.B[0] = Wvb;
    a.bias[0] = bv;
    a.out[0] = vT;
    a.scale = 1.0f;
    gemm_d<4, 2, 2, 2, 2, 2><<<dim3(AD/64, AD/128, 1), dim3(512), 0, stream>>>(a);
  }
  // 3) scores = (qb @ kb^T)/8 -> f32 S over Wkb+Wvb ; 512 blocks
  {
    GemmArgs a = {};
    a.A = qb;
    a.B[0] = kb;
    a.bias[0] = nullptr;
    a.out[0] = S;
    a.scale = SM_SCALE;
    gemm_d<4, 2, 2, 2, 0, 2><<<dim3(AD/64, AD/128, 1), dim3(512), 0, stream>>>(a);
  }
  // 4) row softmax -> P bf16 (over zb)
  softmax_rows<<<dim3(AD), dim3(256), 0, stream>>>(S, P);
  // 5) h = P @ vT^T -> f32 d_out ; 512 blocks
  {
    GemmArgs a = {};
    a.A = P;
    a.B[0] = vT;
    a.bias[0] = nullptr;
    a.out[0] = d_out;
    a.scale = 1.0f;
    gemm_d<4, 2, 2, 2, 0, 2><<<dim3(AD/64, AD/128, 1), dim3(512), 0, stream>>>(a);
  }
}

// Round 13
// 140.757 us; speedup vs baseline: 1.3074x; 1.0028x over previous
//
#include <hip/hip_runtime.h>
#include <hip/hip_bf16.h>

// A=2048 assets, F=2048 flat dim.
//   q = z@Wq^T + bq ; k = z@Wk^T + bk ; v = z@Wv^T + bv
//   S = (q@k^T)/8 ; P = softmax_rows(S) ; h = P@v
// All GEMMs NT (A[m][k].B[n][k]) bf16 MFMA, f32 accum; v materialized as vT.
// Round 13 = round 12 + ONE change: XCD-aware 2D-chunked block swizzle.
//   1D grid; lbid=(bid%8)*(NB/8)+bid/8 -> each XCD gets a contiguous chunk;
//   chunks tile into SBMxSBN block-superblocks whose A+B panels (2+2 MB) fit
//   one XCD's 4MB L2; consecutive superblocks share the B panel.
//
// ws (32 MB) liveness:
//   [0:8)   zb   (dead after V)     -> P  (bf16, after softmax)
//   [8:16)  Wqb  (dead after QK)    -> vT (bf16, written by V)
//   [16:24) Wkb  (dead after QK)    -> S f32 [16:32)
//   [24:32) Wvb  (dead after V)     -> S cont'd
//   d_out: qb[0:8) + kb[8:16) bf16 (dead after scores) -> final h f32 (PV)

#define AD 2048
#define FD 2048
constexpr float SM_SCALE = 0.125f;   // 64^-0.5

typedef __attribute__((ext_vector_type(8))) short bf16x8;
typedef __attribute__((ext_vector_type(4))) float f32x4;

__device__ __forceinline__ unsigned short f2bf(float f) {
  union { float f; unsigned u; } x; x.f = f;
  unsigned r = x.u + 0x7fffu + ((x.u >> 16) & 1u);   // RNE
  return (unsigned short)(r >> 16);
}

typedef __attribute__((address_space(1))) const void GVOID;
typedef __attribute__((address_space(3))) void LVOID;

__device__ __forceinline__ void gload16(const void* g, void* l) {
  __builtin_amdgcn_global_load_lds((GVOID*)g, (LVOID*)l, 16, 0, 0);
}

struct GemmArgs {
  const void* A;
  const void* B[2];
  const float* bias[2];
  void* out[2];
  float scale;
};

// BK=64, dbuf LDS, 8-slot both-sides XOR swizzle (conflict-free, measured 0).
// Wave grid WROWS x WCOLS, wave tile (MREP*16) x (NREP*16).
// Block-index decomposition: NBM x NBN x NZ logical blocks, XCD-chunked with
// SBM x SBN superblocks (bm fastest within; sbm fastest across superblocks).
// MODE: 0 = f32 row-major (xscale), 1 = bf16 row-major (+bias), 2 = bf16 C^T (+bias)
template<int WROWS, int WCOLS, int MREP, int NREP, int MODE, int W2,
         int NBM, int NBN, int NZ, int SBM, int SBN>
__global__ __launch_bounds__(WROWS*WCOLS*64, W2) void gemm_d(GemmArgs args) {
  constexpr int NT = WROWS * WCOLS * 64;
  constexpr int BM = WROWS * MREP * 16;
  constexpr int BN = WCOLS * NREP * 16;
  constexpr int SA = BM * 8;            // 16B slices per A K-tile (BK=64)
  constexpr int SB = BN * 8;
  static_assert(SA >= NT && SA % NT == 0, "A staging full-coverage");
  static_assert(SB % NT == 0, "B staging full-coverage");
  constexpr int NB   = NBM * NBN * NZ;
  constexpr int SBSZ = SBM * SBN;
  constexpr int NSBM = NBM / SBM, NSBN = NBN / SBN;
  static_assert(NB % 8 == 0 && NBM % SBM == 0 && NBN % SBN == 0, "swizzle tiling");

  __shared__ __hip_bfloat16 lA[2][BM * 64];
  __shared__ __hip_bfloat16 lB[2][BN * 64];

  // XCD-chunked bijective swizzle (all divisors compile-time)
  const int bid    = blockIdx.x;
  const int lbid   = (bid & 7) * (NB / 8) + (bid >> 3);
  const int within = lbid % SBSZ;
  const int sb     = lbid / SBSZ;
  const int z      = sb / (NSBM * NSBN);
  const int sbr    = sb % (NSBM * NSBN);
  const int sbm    = sbr % NSBM;        // fastest -> consecutive sbs share B panel
  const int sbn    = sbr / NSBM;
  const int bm     = sbm * SBM + within % SBM;
  const int bn     = sbn * SBN + within / SBM;

  const __hip_bfloat16* __restrict__ A = (const __hip_bfloat16*)args.A;
  const __hip_bfloat16* __restrict__ B = (const __hip_bfloat16*)args.B[z];

  const int t    = threadIdx.x;
  const int lane = t & 63;
  const int wv   = t >> 6;
  const int wr   = wv / WCOLS;
  const int wc   = wv % WCOLS;
  const int fr   = lane & 15;
  const int s2   = lane >> 4;          // logical 16B k-group 0..3 (within K=32)

  f32x4 acc[MREP][NREP] = {};

  // swizzled source column (elements) for slice s: row = s>>3, phys slot = s&7
  // holds logical slot (s&7) ^ (row&7)
  auto scol = [](int s) { return (((s & 7) ^ ((s >> 3) & 7)) * 8); };

  auto STAGE = [&](int k0, int buf) {
    #pragma unroll
    for (int r = 0; r < SA / NT; ++r) {
      const int s = t + r * NT;
      gload16(A + (size_t)(bm * BM + (s >> 3)) * FD + k0 + scol(s), &lA[buf][s * 8]);
    }
    #pragma unroll
    for (int r = 0; r < SB / NT; ++r) {
      const int s = t + r * NT;
      gload16(B + (size_t)(bn * BN + (s >> 3)) * FD + k0 + scol(s), &lB[buf][s * 8]);
    }
  };

  auto COMPUTE = [&](int buf) {
    #pragma unroll
    for (int kk = 0; kk < 2; ++kk) {       // two K=32 sub-steps per BK=64 tile
      const int ls = s2 + 4 * kk;          // logical slot 0..7
      bf16x8 af[MREP], bfr[NREP];
      #pragma unroll
      for (int m = 0; m < MREP; ++m) {
        const int row = wr * (MREP * 16) + m * 16 + fr;
        af[m] = *reinterpret_cast<const bf16x8*>(
            &lA[buf][row * 64 + ((ls ^ (row & 7)) * 8)]);
      }
      #pragma unroll
      for (int n = 0; n < NREP; ++n) {
        const int row = wc * (NREP * 16) + n * 16 + fr;
        bfr[n] = *reinterpret_cast<const bf16x8*>(
            &lB[buf][row * 64 + ((ls ^ (row & 7)) * 8)]);
      }
      #pragma unroll
      for (int m = 0; m < MREP; ++m)
        #pragma unroll
        for (int n = 0; n < NREP; ++n)
          acc[m][n] = __builtin_amdgcn_mfma_f32_16x16x32_bf16(af[m], bfr[n], acc[m][n], 0, 0, 0);
    }
  };

  STAGE(0, 0);
  __syncthreads();
  int cur = 0;
  for (int k0 = 64; k0 < FD; k0 += 64) {
    STAGE(k0, cur ^ 1);     // prefetch next tile (in flight during COMPUTE)
    COMPUTE(cur);
    __syncthreads();        // drains prefetch + all frag reads of cur
    cur ^= 1;
  }
  COMPUTE(cur);

  // Epilogue. C/D mapping (m89-verified): col = lane&15, row = (lane>>4)*4 + j
  const float scale = args.scale;
  const float* __restrict__ bias = args.bias[z];
  const int row0 = bm * BM + wr * (MREP * 16) + (lane >> 4) * 4;
  const int col0 = bn * BN + wc * (NREP * 16) + fr;

  if constexpr (MODE == 0) {
    float* __restrict__ out = (float*)args.out[z];
    #pragma unroll
    for (int m = 0; m < MREP; ++m)
      #pragma unroll
      for (int n = 0; n < NREP; ++n) {
        const int cg = col0 + n * 16;
        #pragma unroll
        for (int j = 0; j < 4; ++j)
          out[(size_t)(row0 + m * 16 + j) * FD + cg] = acc[m][n][j] * scale;
      }
  } else if constexpr (MODE == 1) {
    __hip_bfloat16* __restrict__ out = (__hip_bfloat16*)args.out[z];
    #pragma unroll
    for (int m = 0; m < MREP; ++m)
      #pragma unroll
      for (int n = 0; n < NREP; ++n) {
        const int cg = col0 + n * 16;
        const float badd = bias[cg];
        #pragma unroll
        for (int j = 0; j < 4; ++j) {
          unsigned short b16 = f2bf(acc[m][n][j] + badd);
          out[(size_t)(row0 + m * 16 + j) * FD + cg] = *reinterpret_cast<__hip_bfloat16*>(&b16);
        }
      }
  } else { // MODE == 2: store C^T -> vT[f][a]; 4 consecutive rows = one 8B store
    __hip_bfloat16* __restrict__ out = (__hip_bfloat16*)args.out[z];
    #pragma unroll
    for (int m = 0; m < MREP; ++m)
      #pragma unroll
      for (int n = 0; n < NREP; ++n) {
        const int cg = col0 + n * 16;   // F index -> row of vT
        const int rg = row0 + m * 16;   // asset index -> col of vT
        const float badd = bias[cg];
        ushort4 pk;
        pk.x = f2bf(acc[m][n][0] + badd);
        pk.y = f2bf(acc[m][n][1] + badd);
        pk.z = f2bf(acc[m][n][2] + badd);
        pk.w = f2bf(acc[m][n][3] + badd);
        *reinterpret_cast<ushort4*>(out + (size_t)cg * AD + rg) = pk;
      }
  }
}

// convert z, Wq, Wk, Wv (f32) -> bf16 [zb | Wqb | Wkb | Wvb], 4M elems each
__global__ __launch_bounds__(256) void cvt_bf16(const float* __restrict__ z,
                                                const float* __restrict__ wq,
                                                const float* __restrict__ wk,
                                                const float* __restrict__ wv,
                                                __hip_bfloat16* __restrict__ dst) {
  const size_t NITEM = (size_t)4 * 4096 * 1024 / 8;
  const size_t step = (size_t)gridDim.x * blockDim.x;
  for (size_t idx = (size_t)blockIdx.x * blockDim.x + threadIdx.x; idx < NITEM; idx += step) {
    const int ten = (int)(idx >> 19);
    const size_t off = (idx & ((1u << 19) - 1)) * 8;
    const float* src = (ten == 0) ? z : (ten == 1) ? wq : (ten == 2) ? wk : wv;
    const float4 a = *reinterpret_cast<const float4*>(src + off);
    const float4 b = *reinterpret_cast<const float4*>(src + off + 4);
    union { unsigned short us[8]; int4 v; } pk;
    pk.us[0] = f2bf(a.x); pk.us[1] = f2bf(a.y); pk.us[2] = f2bf(a.z); pk.us[3] = f2bf(a.w);
    pk.us[4] = f2bf(b.x); pk.us[5] = f2bf(b.y); pk.us[6] = f2bf(b.z); pk.us[7] = f2bf(b.w);
    *reinterpret_cast<int4*>(dst + (size_t)ten * 4096 * 1024 + off) = pk.v;
  }
}

__global__ __launch_bounds__(256) void softmax_rows(const float* __restrict__ S,
                                                    __hip_bfloat16* __restrict__ P) {
  const int row = blockIdx.x;
  const int t = threadIdx.x;
  const float* s = S + (size_t)row * AD + t * 8;
  const float4 v0 = *reinterpret_cast<const float4*>(s);
  const float4 v1 = *reinterpret_cast<const float4*>(s + 4);
  float vals[8] = {v0.x, v0.y, v0.z, v0.w, v1.x, v1.y, v1.z, v1.w};

  float m = vals[0];
  #pragma unroll
  for (int j = 1; j < 8; ++j) m = fmaxf(m, vals[j]);
  #pragma unroll
  for (int off = 32; off >= 1; off >>= 1) m = fmaxf(m, __shfl_xor(m, off));

  __shared__ float redm[4], reds[4];
  if ((t & 63) == 0) redm[t >> 6] = m;
  __syncthreads();
  m = fmaxf(fmaxf(redm[0], redm[1]), fmaxf(redm[2], redm[3]));

  float e[8];
  float sum = 0.f;
  #pragma unroll
  for (int j = 0; j < 8; ++j) { e[j] = __expf(vals[j] - m); sum += e[j]; }
  #pragma unroll
  for (int off = 32; off >= 1; off >>= 1) sum += __shfl_xor(sum, off);
  if ((t & 63) == 0) reds[t >> 6] = sum;
  __syncthreads();
  sum = reds[0] + reds[1] + reds[2] + reds[3];
  const float inv = 1.f / sum;

  union { unsigned short us[8]; int4 v; } pk;
  #pragma unroll
  for (int j = 0; j < 8; ++j) pk.us[j] = f2bf(e[j] * inv);
  *reinterpret_cast<int4*>(P + (size_t)row * AD + t * 8) = pk.v;
}

extern "C" void kernel_launch(void* const* d_in, const int* in_sizes, int n_in,
                              void* d_out, int out_size, void* d_ws, size_t ws_size,
                              hipStream_t stream) {
  const float* z  = (const float*)d_in[0];
  const float* Wq = (const float*)d_in[1];
  const float* bq = (const float*)d_in[2];
  const float* Wk = (const float*)d_in[3];
  const float* bk = (const float*)d_in[4];
  const float* Wv = (const float*)d_in[5];
  const float* bv = (const float*)d_in[6];

  char* ws = (char*)d_ws;
  const size_t MB8 = (size_t)8 * 1024 * 1024;
  __hip_bfloat16* zb  = (__hip_bfloat16*)(ws);            // dead after V
  __hip_bfloat16* Wqb = (__hip_bfloat16*)(ws + MB8);      // dead after QK
  __hip_bfloat16* Wkb = (__hip_bfloat16*)(ws + 2*MB8);    // dead after QK
  __hip_bfloat16* Wvb = (__hip_bfloat16*)(ws + 3*MB8);    // dead after V
  __hip_bfloat16* vT  = (__hip_bfloat16*)(ws + MB8);      // over Wqb
  float*          S   = (float*)(ws + 2*MB8);             // over Wkb+Wvb (16MB)
  __hip_bfloat16* P   = (__hip_bfloat16*)(ws);            // over zb
  __hip_bfloat16* qb  = (__hip_bfloat16*)d_out;           // d_out scratch [0:8)MB
  __hip_bfloat16* kb  = (__hip_bfloat16*)d_out + (size_t)AD * FD;  // [8:16)MB

  // 0) convert all four tensors to bf16
  cvt_bf16<<<dim3(2048), dim3(256), 0, stream>>>(z, Wq, Wk, Wv, (__hip_bfloat16*)ws);

  // 1) fused QK (pure bf16): (2,4,4,2) 128^2 BK=64, 512 blocks, XCD-chunked 4x4
  {
    GemmArgs a;
    a.A = zb;
    a.B[0] = Wqb;  a.B[1] = Wkb;
    a.bias[0] = bq; a.bias[1] = bk;
    a.out[0] = qb;  a.out[1] = kb;
    a.scale = 1.0f;
    gemm_d<2, 4, 4, 2, 1, 2, 16, 16, 2, 4, 4>
        <<<dim3(512), dim3(512), 0, stream>>>(a);
  }
  // 2) V (pure bf16): (4,2,2,2) 128x64 BK=64, 512 blocks, XCD-chunked 4x8 -> vT
  {
    GemmArgs a = {};
    a.A = zb;
    a.B[0] = Wvb;
    a.bias[0] = bv;
    a.out[0] = vT;
    a.scale = 1.0f;
    gemm_d<4, 2, 2, 2, 2, 2, 16, 32, 1, 4, 8>
        <<<dim3(512), dim3(512), 0, stream>>>(a);
  }
  // 3) scores = (qb @ kb^T)/8 -> f32 S over Wkb+Wvb ; 512 blocks
  {
    GemmArgs a = {};
    a.A = qb;
    a.B[0] = kb;
    a.bias[0] = nullptr;
    a.out[0] = S;
    a.scale = SM_SCALE;
    gemm_d<4, 2, 2, 2, 0, 2, 16, 32, 1, 4, 8>
        <<<dim3(512), dim3(512), 0, stream>>>(a);
  }
  // 4) row softmax -> P bf16 (over zb)
  softmax_rows<<<dim3(AD), dim3(256), 0, stream>>>(S, P);
  // 5) h = P @ vT^T -> f32 d_out ; 512 blocks
  {
    GemmArgs a = {};
    a.A = P;
    a.B[0] = vT;
    a.bias[0] = nullptr;
    a.out[0] = d_out;
    a.scale = 1.0f;
    gemm_d<4, 2, 2, 2, 0, 2, 16, 32, 1, 4, 8>
        <<<dim3(512), dim3(512), 0, stream>>>(a);
  }
}